// Round 11
// baseline (271.748 us; speedup 1.0000x reference)
//
#include <hip/hip_runtime.h>
#include <hip/hip_bf16.h>
#include <math.h>

#define D_MODEL 1024
#define D_STATE 16
#define D_CONV  4
#define BATCH   2
#define SEQ     2048
#define MROWS   (BATCH * SEQ)   // 4096
#define CHUNK   32
#define NCHUNK  (SEQ / CHUNK)   // 64
#define BD      (BATCH * D_MODEL)   // 2048

typedef __attribute__((ext_vector_type(8))) short bf16x8;
typedef __attribute__((ext_vector_type(4))) float f32x4;

__device__ __forceinline__ unsigned short f2bf(float f) {
    unsigned int u = __builtin_bit_cast(unsigned int, f);
    u = (u + 0x7fffu + ((u >> 16) & 1u)) >> 16;
    return (unsigned short)u;
}
__device__ __forceinline__ float bf2f(unsigned short u) {
    return __builtin_bit_cast(float, (unsigned int)u << 16);
}
__device__ __forceinline__ float softplus_f(float v) {
    return (v > 20.f) ? v : log1pf(expf(v));
}

// async global->LDS, 16 bytes per lane; LDS dest = wave-uniform base + lane*16
__device__ __forceinline__ void gl2lds16(const unsigned short* g, unsigned short* l) {
    __builtin_amdgcn_global_load_lds(
        (__attribute__((address_space(1))) void*)(void*)g,
        (__attribute__((address_space(3))) void*)(void*)l, 16, 0, 0);
}

// raw barriers (no __syncthreads -> no compiler-forced vmcnt(0) drain).
// simm16: vmcnt[3:0] | expcnt[2:0]<<4 | lgkmcnt[3:0]<<8 | vmcnt[5:4]<<14
// keep6: wait until <=6 vmem outstanding (drains oldest tile only)
__device__ __forceinline__ void pipe_barrier_keep6() {
    asm volatile("" ::: "memory");
    __builtin_amdgcn_s_waitcnt(0x0F76);   // vmcnt(6), lgkm no-wait, exp no-wait
    __builtin_amdgcn_s_barrier();
    asm volatile("" ::: "memory");
}
__device__ __forceinline__ void pipe_barrier_drain() {
    asm volatile("" ::: "memory");
    __builtin_amdgcn_s_waitcnt(0x0F70);   // vmcnt(0), lgkm no-wait
    __builtin_amdgcn_s_barrier();
    asm volatile("" ::: "memory");
}

// ---------------------------------------------------------------------------
// Merged prepass (unchanged)
// ---------------------------------------------------------------------------
__global__ __launch_bounds__(256) void prepass(
        const float* __restrict__ x, unsigned short* __restrict__ xb,
        const float* __restrict__ W_in, unsigned short* __restrict__ Wt_in,
        const float* __restrict__ W_dt, unsigned short* __restrict__ Wt_cat,
        const float* __restrict__ W_out, unsigned short* __restrict__ Wt_out,
        const float* __restrict__ Wx) {
    __shared__ float tile[32][33];
    const int blk = blockIdx.x;
    const int tid = threadIdx.x;

    if (blk < 2048) {                       // region 0: cvt x
        const size_t i = ((size_t)blk * 256 + tid) * 8;
        const float4 v0 = *(const float4*)(x + i);
        const float4 v1 = *(const float4*)(x + i + 4);
        bf16x8 o;
        o[0] = (short)f2bf(v0.x); o[1] = (short)f2bf(v0.y);
        o[2] = (short)f2bf(v0.z); o[3] = (short)f2bf(v0.w);
        o[4] = (short)f2bf(v1.x); o[5] = (short)f2bf(v1.y);
        o[6] = (short)f2bf(v1.z); o[7] = (short)f2bf(v1.w);
        *(bf16x8*)(xb + i) = o;
        return;
    }
    if (blk < 2048 + 2048 + 1024 + 1024) {  // regions 1-3: transpose
        const float* W; unsigned short* Wt; int N, b;
        if (blk < 4096)      { W = W_in;  Wt = Wt_in;  N = 2048; b = blk - 2048; }
        else if (blk < 5120) { W = W_dt;  Wt = Wt_cat; N = 1024; b = blk - 4096; }
        else                 { W = W_out; Wt = Wt_out; N = 1024; b = blk - 5120; }
        const int nx = N / 32;
        const int n0 = (b % nx) * 32, k0 = (b / nx) * 32;
        const int tx = tid & 31, ty = tid >> 5;
#pragma unroll
        for (int r = 0; r < 4; ++r)
            tile[ty + r * 8][tx] = W[(size_t)(k0 + ty + r * 8) * N + n0 + tx];
        __syncthreads();
#pragma unroll
        for (int r = 0; r < 4; ++r)
            Wt[(size_t)(n0 + ty + r * 8) * 1024 + k0 + tx] = f2bf(tile[tx][ty + r * 8]);
        return;
    }
    {                                        // region 4: wx_stage
        const int idx = (blk - 6144) * 256 + tid;
        const int k = idx & 1023;
        const int n = idx >> 10;
        unsigned short v = 0;
        if (n < 32) v = f2bf(Wx[(size_t)k * 32 + n]);
        Wt_cat[(size_t)(1024 + n) * 1024 + k] = v;
    }
}

// ---------------------------------------------------------------------------
// MFMA GEMM: 64(M) x 128(N) tile, BK=64, 4 waves, global_load_lds staging,
// TRIPLE-buffered LDS + raw vmcnt(6) barriers:
//   iter i: stage tile i+2 -> buf[(i+2)%3]; compute tile i from buf[i%3];
//           s_waitcnt vmcnt(6) (drains tile i+1 only) + s_barrier.
// Loads get ~2 full iterations in flight before their wait (covers HBM lat).
// No __syncthreads in the loop -> compiler never inserts the vmcnt(0) drain.
// Buf-reuse safety: at each barrier all waves' ds_reads of the 2-iter-old buf
// completed (compiler waits lgkmcnt before MFMA uses, which precede arrival).
// EPI: 0 fp32 store, 2 bf16 store, 3 fused dt/BC.
// ---------------------------------------------------------------------------
#define STAGE_TILE(ko, Ab, Bb)                       \
    do {                                             \
        gl2lds16(AgL + (ko), (Ab) + sT);             \
        gl2lds16(AgH + (ko), (Ab) + 2048 + sT);      \
        gl2lds16(Bg0L + (ko), (Bb) + sT);            \
        gl2lds16(Bg1L + (ko), (Bb) + 2048 + sT);     \
        gl2lds16(Bg0H + (ko), (Bb) + 4096 + sT);     \
        gl2lds16(Bg1H + (ko), (Bb) + 6144 + sT);     \
    } while (0)

template <int EPI>
__global__ __launch_bounds__(256) void gemm64(
        const unsigned short* __restrict__ A, const unsigned short* __restrict__ Bt,
        void* __restrict__ Cout, int N, int K,
        const float* __restrict__ bias, const float* __restrict__ alog,
        float* __restrict__ bc) {
    __shared__ unsigned short As[3 * 4096];   // 3 bufs x (64 rows x 64k as 2 half-K) 24 KB
    __shared__ unsigned short Bs[3 * 8192];   // 3 bufs x (128 rows x 64k)           48 KB

    const int tid  = threadIdx.x;
    const int wave = tid >> 6, lane = tid & 63;
    const int q = lane >> 4, mr = lane & 15;
    const int m0 = blockIdx.y * 64, n0 = blockIdx.x * 128;

    f32x4 acc[4][2];
#pragma unroll
    for (int mi = 0; mi < 4; ++mi)
#pragma unroll
        for (int ni = 0; ni < 2; ++ni) acc[mi][ni] = {0.f, 0.f, 0.f, 0.f};

    const int kb = (tid & 3) * 8;
    const int rT = tid >> 2;
    const unsigned short* AgL  = A + (size_t)(m0 + rT) * K + kb;
    const unsigned short* AgH  = AgL + 32;
    const unsigned short* Bg0L = Bt + (size_t)(n0 + rT) * K + kb;
    const unsigned short* Bg0H = Bg0L + 32;
    const unsigned short* Bg1L = Bt + (size_t)(n0 + 64 + rT) * K + kb;
    const unsigned short* Bg1H = Bg1L + 32;
    const int sT = tid * 8;

    const int NK = K >> 6;   // 16

    // prologue: stage tiles 0,1 -> bufs 0,1; wait tile0 (oldest 6), keep tile1 flying
    STAGE_TILE(0, As, Bs);
    STAGE_TILE(64, As + 4096, Bs + 8192);
    pipe_barrier_keep6();

    int cur = 0, pf = 2;
    for (int i = 0; i < NK; ++i) {
        unsigned short* Ac = As + cur * 4096;
        unsigned short* Bc = Bs + cur * 8192;
        const bool havePF = (i + 2 < NK);
        if (havePF)
            STAGE_TILE((i + 2) * 64, As + pf * 4096, Bs + pf * 8192);

#pragma unroll
        for (int ks = 0; ks < 2; ++ks) {
            bf16x8 af[4], bfr[2];
#pragma unroll
            for (int mi = 0; mi < 4; ++mi)
                af[mi] = *(const bf16x8*)(Ac + ks * 2048 + (mi * 16 + mr) * 32 + q * 8);
#pragma unroll
            for (int ni = 0; ni < 2; ++ni)
                bfr[ni] = *(const bf16x8*)(Bc + ks * 4096 +
                                           (wave * 32 + ni * 16 + mr) * 32 + q * 8);
#pragma unroll
            for (int mi = 0; mi < 4; ++mi)
#pragma unroll
                for (int ni = 0; ni < 2; ++ni)
                    acc[mi][ni] = __builtin_amdgcn_mfma_f32_16x16x32_bf16(
                        af[mi], bfr[ni], acc[mi][ni], 0, 0, 0);
        }

        if (i + 1 < NK) {
            if (havePF) pipe_barrier_keep6();   // drains tile i+1 only
            else        pipe_barrier_drain();   // last prefetch: drain it fully
        }
        cur = (cur == 2) ? 0 : cur + 1;
        pf  = (pf == 2) ? 0 : pf + 1;
    }

    // epilogue: C/D layout col = lane&15, row = q*4 + r
#pragma unroll
    for (int ni = 0; ni < 2; ++ni) {
        const int col = n0 + wave * 32 + ni * 16 + mr;
        float be = 0.f, al = 0.f;
        if (EPI == 3 && col < 1024) { be = bias[col]; al = alog[col]; }
#pragma unroll
        for (int mi = 0; mi < 4; ++mi) {
            const int row0 = m0 + mi * 16 + q * 4;
#pragma unroll
            for (int r = 0; r < 4; ++r) {
                float v = acc[mi][ni][r];
                const int row = row0 + r;
                if (EPI == 0) {
                    ((float*)Cout)[(size_t)row * N + col] = v;
                } else if (EPI == 2) {
                    ((unsigned short*)Cout)[(size_t)row * N + col] = f2bf(v);
                } else {  // EPI == 3
                    if (col < 1024) {
                        float dt = softplus_f(v + be);
                        ((unsigned short*)Cout)[(size_t)row * 1024 + col] =
                            f2bf(expf(dt * (-expf(al))));
                    } else if (col < 1056) {
                        bc[(size_t)row * 32 + (col - 1024)] = v;
                    }
                }
            }
        }
    }
}

// ---------------------------------------------------------------------------
// Depthwise causal conv (4 taps) + bias + SiLU, bf16 in/out. 8 channels/thread.
// ---------------------------------------------------------------------------
__global__ __launch_bounds__(256) void conv_silu_kernel(
        const unsigned short* __restrict__ xz, const float* __restrict__ conv_w,
        const float* __restrict__ conv_b, unsigned short* __restrict__ xssm) {
    const int idx = blockIdx.x * 256 + threadIdx.x;
    const int d8 = idx & 127;
    const int bt = idx >> 7;
    const int t  = bt & (SEQ - 1);
    const int d  = d8 * 8;

    float4 w[8];
#pragma unroll
    for (int i = 0; i < 8; ++i) w[i] = *(const float4*)&conv_w[(d + i) * 4];

    float acc[8];
    {
        const float4 b0 = *(const float4*)&conv_b[d];
        const float4 b1 = *(const float4*)&conv_b[d + 4];
        acc[0] = b0.x; acc[1] = b0.y; acc[2] = b0.z; acc[3] = b0.w;
        acc[4] = b1.x; acc[5] = b1.y; acc[6] = b1.z; acc[7] = b1.w;
    }

#pragma unroll
    for (int j = 0; j < D_CONV; ++j) {
        const int tt = t - (D_CONV - 1) + j;
        if (tt < 0) continue;
        const bf16x8 xv = *(const bf16x8*)(&xz[((size_t)(bt - t + tt)) * 2048 + d]);
        const float wj[8] = {j == 0 ? w[0].x : j == 1 ? w[0].y : j == 2 ? w[0].z : w[0].w,
                             j == 0 ? w[1].x : j == 1 ? w[1].y : j == 2 ? w[1].z : w[1].w,
                             j == 0 ? w[2].x : j == 1 ? w[2].y : j == 2 ? w[2].z : w[2].w,
                             j == 0 ? w[3].x : j == 1 ? w[3].y : j == 2 ? w[3].z : w[3].w,
                             j == 0 ? w[4].x : j == 1 ? w[4].y : j == 2 ? w[4].z : w[4].w,
                             j == 0 ? w[5].x : j == 1 ? w[5].y : j == 2 ? w[5].z : w[5].w,
                             j == 0 ? w[6].x : j == 1 ? w[6].y : j == 2 ? w[6].z : w[6].w,
                             j == 0 ? w[7].x : j == 1 ? w[7].y : j == 2 ? w[7].z : w[7].w};
#pragma unroll
        for (int i = 0; i < 8; ++i)
            acc[i] += bf2f((unsigned short)xv[i]) * wj[i];
    }
    bf16x8 o;
#pragma unroll
    for (int i = 0; i < 8; ++i) {
        const float s = acc[i] / (1.f + expf(-acc[i]));
        o[i] = (short)f2bf(s);
    }
    *(bf16x8*)(&xssm[(size_t)bt * D_MODEL + d]) = o;
}

// ---------------------------------------------------------------------------
// Chunked selective scan (unchanged)
// ---------------------------------------------------------------------------
__global__ __launch_bounds__(256) void scan_pass1(
        const unsigned short* __restrict__ xssm, const unsigned short* __restrict__ dA16,
        const float* __restrict__ BCb,
        float* __restrict__ Sbuf, float* __restrict__ Pbuf) {
    const int ch = blockIdx.x, dg = blockIdx.y, b = blockIdx.z;
    const int tid = threadIdx.x;
    const int dd  = dg * 256 + tid;
    const int t0  = ch * CHUNK;

    __shared__ float Bs[CHUNK][16];
    if (tid < CHUNK * 4) {
        const int t = tid >> 2, j = (tid & 3) * 4;
        *(float4*)&Bs[t][j] = *(const float4*)&BCb[((size_t)b * SEQ + t0 + t) * 32 + j];
    }
    __syncthreads();

    const size_t base = ((size_t)b * SEQ + t0) * D_MODEL + dd;
    float h[16];
#pragma unroll
    for (int n = 0; n < 16; ++n) h[n] = 0.f;
    float P = 1.f;

    for (int g = 0; g < CHUNK; g += 8) {
        float dAr[8], xr[8];
#pragma unroll
        for (int p = 0; p < 8; ++p) {
            const size_t o = base + (size_t)(g + p) * D_MODEL;
            dAr[p] = bf2f(dA16[o]);
            xr[p]  = bf2f(xssm[o]);
        }
#pragma unroll
        for (int p = 0; p < 8; ++p) {
            const int t = g + p;
            const float dA = dAr[p], x = xr[p];
            P *= dA;
            const float4 B0 = *(const float4*)&Bs[t][0];
            const float4 B1 = *(const float4*)&Bs[t][4];
            const float4 B2 = *(const float4*)&Bs[t][8];
            const float4 B3 = *(const float4*)&Bs[t][12];
            h[0]  = h[0]  * dA + x * B0.x;  h[1]  = h[1]  * dA + x * B0.y;
            h[2]  = h[2]  * dA + x * B0.z;  h[3]  = h[3]  * dA + x * B0.w;
            h[4]  = h[4]  * dA + x * B1.x;  h[5]  = h[5]  * dA + x * B1.y;
            h[6]  = h[6]  * dA + x * B1.z;  h[7]  = h[7]  * dA + x * B1.w;
            h[8]  = h[8]  * dA + x * B2.x;  h[9]  = h[9]  * dA + x * B2.y;
            h[10] = h[10] * dA + x * B2.z;  h[11] = h[11] * dA + x * B2.w;
            h[12] = h[12] * dA + x * B3.x;  h[13] = h[13] * dA + x * B3.y;
            h[14] = h[14] * dA + x * B3.z;  h[15] = h[15] * dA + x * B3.w;
        }
    }

    const int dn = b * D_MODEL + dd;
    const size_t so = ((size_t)ch * BD + dn) * 16;
#pragma unroll
    for (int n = 0; n < 16; n += 4)
        *(float4*)&Sbuf[so + n] = make_float4(h[n], h[n + 1], h[n + 2], h[n + 3]);
    Pbuf[(size_t)ch * BD + dn] = P;
}

__global__ __launch_bounds__(128) void scan_mid(
        const float* __restrict__ Sbuf, const float* __restrict__ Pbuf,
        float* __restrict__ Hin) {
    const int idx = blockIdx.x * 128 + threadIdx.x;
    const int n   = idx & 15;
    const int dn  = idx >> 4;

    float h = 0.f;
    for (int ch = 0; ch < NCHUNK; ++ch) {
        const size_t s = ((size_t)ch * BD + dn) * 16 + n;
        Hin[s] = h;
        h = Pbuf[(size_t)ch * BD + dn] * h + Sbuf[s];
    }
}

__global__ __launch_bounds__(256) void scan_pass2(
        const unsigned short* __restrict__ xssm, const unsigned short* __restrict__ dA16,
        const float* __restrict__ BCb, const unsigned short* __restrict__ xz,
        const float* __restrict__ Dp, const float* __restrict__ Hin,
        unsigned short* __restrict__ ybuf) {
    const int ch = blockIdx.x, dg = blockIdx.y, b = blockIdx.z;
    const int tid = threadIdx.x;
    const int dd  = dg * 256 + tid;
    const int t0  = ch * CHUNK;

    __shared__ float BCs[CHUNK][32];
    {
        const int t = tid >> 3, j = (tid & 7) * 4;
        *(float4*)&BCs[t][j] = *(const float4*)&BCb[((size_t)b * SEQ + t0 + t) * 32 + j];
    }
    __syncthreads();

    const float Dpv = Dp[dd];
    const size_t base  = ((size_t)b * SEQ + t0) * D_MODEL + dd;
    const size_t baseZ = ((size_t)b * SEQ + t0) * 2048 + D_MODEL + dd;

    float h[16];
    const int dn = b * D_MODEL + dd;
    const size_t ho = ((size_t)ch * BD + dn) * 16;
#pragma unroll
    for (int n = 0; n < 16; n += 4) {
        const float4 hv = *(const float4*)&Hin[ho + n];
        h[n] = hv.x; h[n + 1] = hv.y; h[n + 2] = hv.z; h[n + 3] = hv.w;
    }

    for (int g = 0; g < CHUNK; g += 8) {
        float dAr[8], xr[8], zr[8];
#pragma unroll
        for (int p = 0; p < 8; ++p) {
            const size_t o = base + (size_t)(g + p) * D_MODEL;
            dAr[p] = bf2f(dA16[o]);
            xr[p]  = bf2f(xssm[o]);
            zr[p]  = bf2f(xz[baseZ + (size_t)(g + p) * 2048]);
        }
#pragma unroll
        for (int p = 0; p < 8; ++p) {
            const int t = g + p;
            const float dA = dAr[p], x = xr[p];
            const float4 B0 = *(const float4*)&BCs[t][0];
            const float4 B1 = *(const float4*)&BCs[t][4];
            const float4 B2 = *(const float4*)&BCs[t][8];
            const float4 B3 = *(const float4*)&BCs[t][12];
            const float4 C0 = *(const float4*)&BCs[t][16];
            const float4 C1 = *(const float4*)&BCs[t][20];
            const float4 C2 = *(const float4*)&BCs[t][24];
            const float4 C3 = *(const float4*)&BCs[t][28];
            float y = 0.f;
            h[0]  = h[0]  * dA + x * B0.x;  y += h[0]  * C0.x;
            h[1]  = h[1]  * dA + x * B0.y;  y += h[1]  * C0.y;
            h[2]  = h[2]  * dA + x * B0.z;  y += h[2]  * C0.z;
            h[3]  = h[3]  * dA + x * B0.w;  y += h[3]  * C0.w;
            h[4]  = h[4]  * dA + x * B1.x;  y += h[4]  * C1.x;
            h[5]  = h[5]  * dA + x * B1.y;  y += h[5]  * C1.y;
            h[6]  = h[6]  * dA + x * B1.z;  y += h[6]  * C1.z;
            h[7]  = h[7]  * dA + x * B1.w;  y += h[7]  * C1.w;
            h[8]  = h[8]  * dA + x * B2.x;  y += h[8]  * C2.x;
            h[9]  = h[9]  * dA + x * B2.y;  y += h[9]  * C2.y;
            h[10] = h[10] * dA + x * B2.z;  y += h[10] * C2.z;
            h[11] = h[11] * dA + x * B2.w;  y += h[11] * C2.w;
            h[12] = h[12] * dA + x * B3.x;  y += h[12] * C3.x;
            h[13] = h[13] * dA + x * B3.y;  y += h[13] * C3.y;
            h[14] = h[14] * dA + x * B3.z;  y += h[14] * C3.z;
            h[15] = h[15] * dA + x * B3.w;  y += h[15] * C3.w;

            const float zv = zr[p];
            const float sz = zv / (1.f + expf(-zv));
            ybuf[base + (size_t)t * D_MODEL] = f2bf((y + x * Dpv) * sz);
        }
    }
}

// ---------------------------------------------------------------------------
extern "C" void kernel_launch(void* const* d_in, const int* in_sizes, int n_in,
                              void* d_out, int out_size, void* d_ws, size_t ws_size,
                              hipStream_t stream) {
    const float* x       = (const float*)d_in[0];
    const float* W_in    = (const float*)d_in[1];
    const float* conv_w  = (const float*)d_in[2];
    const float* conv_b  = (const float*)d_in[3];
    const float* W_x     = (const float*)d_in[4];
    const float* W_dt    = (const float*)d_in[5];
    const float* b_dt    = (const float*)d_in[6];
    const float* A_log   = (const float*)d_in[7];
    const float* D_param = (const float*)d_in[8];
    const float* W_out   = (const float*)d_in[9];
    float* out = (float*)d_out;
    char* ws   = (char*)d_ws;

    unsigned short* xz_bf   = (unsigned short*)(ws + 0);
    unsigned short* xssm_bf = (unsigned short*)(ws + 16777216);
    unsigned short* dAb16   = (unsigned short*)(ws + 25165824);
    float*          BCb     = (float*)(ws + 41943040);
    unsigned short* ybuf_bf = (unsigned short*)(ws + 42467328);
    unsigned short* xb      = (unsigned short*)(ws + 50855936);
    unsigned short* Wt_in   = (unsigned short*)(ws + 59244544);
    unsigned short* Wt_cat  = (unsigned short*)(ws + 63438848);
    unsigned short* Wt_out  = (unsigned short*)(ws + 65798144);
    float*          Sbuf    = (float*)(ws + 67895296);
    float*          Pbuf    = (float*)(ws + 76283904);
    float*          Hin     = (float*)(ws + 76808192);

    // 0. merged prepass
    prepass<<<2048 + 2048 + 1024 + 1024 + 512, 256, 0, stream>>>(
        x, xb, W_in, Wt_in, W_dt, Wt_cat, W_out, Wt_out, W_x);

    // 1. xz = x @ W_in  (bf16 out)
    gemm64<2><<<dim3(2048 / 128, MROWS / 64), 256, 0, stream>>>(
        xb, Wt_in, xz_bf, 2048, D_MODEL, nullptr, nullptr, nullptr);
    // 2. depthwise conv + silu
    conv_silu_kernel<<<(MROWS * 128) / 256, 256, 0, stream>>>(xz_bf, conv_w, conv_b, xssm_bf);
    // 3. fused dt/BC GEMM
    gemm64<3><<<dim3(1152 / 128, MROWS / 64), 256, 0, stream>>>(
        xssm_bf, Wt_cat, dAb16, 1152, D_MODEL, b_dt, A_log, BCb);
    // 4. chunked selective scan
    scan_pass1<<<dim3(NCHUNK, D_MODEL / 256, BATCH), 256, 0, stream>>>(
        xssm_bf, dAb16, BCb, Sbuf, Pbuf);
    scan_mid<<<(BD * 16) / 128, 128, 0, stream>>>(Sbuf, Pbuf, Hin);
    scan_pass2<<<dim3(NCHUNK, D_MODEL / 256, BATCH), 256, 0, stream>>>(
        xssm_bf, dAb16, BCb, xz_bf, D_param, Hin, ybuf_bf);
    // 5. out = y @ W_out
    gemm64<0><<<dim3(1024 / 128, MROWS / 64), 256, 0, stream>>>(
        ybuf_bf, Wt_out, out, D_MODEL, D_MODEL, nullptr, nullptr, nullptr);
}

// Round 12
// 238.129 us; speedup vs baseline: 1.1412x; 1.1412x over previous
//
#include <hip/hip_runtime.h>
#include <hip/hip_bf16.h>
#include <math.h>

#define D_MODEL 1024
#define D_STATE 16
#define D_CONV  4
#define BATCH   2
#define SEQ     2048
#define MROWS   (BATCH * SEQ)   // 4096
#define CHUNK   32
#define NCHUNK  (SEQ / CHUNK)   // 64
#define BD      (BATCH * D_MODEL)   // 2048

typedef __attribute__((ext_vector_type(8))) short bf16x8;
typedef __attribute__((ext_vector_type(4))) float f32x4;

__device__ __forceinline__ unsigned short f2bf(float f) {
    unsigned int u = __builtin_bit_cast(unsigned int, f);
    u = (u + 0x7fffu + ((u >> 16) & 1u)) >> 16;
    return (unsigned short)u;
}
__device__ __forceinline__ float bf2f(unsigned short u) {
    return __builtin_bit_cast(float, (unsigned int)u << 16);
}
__device__ __forceinline__ float softplus_f(float v) {
    return (v > 20.f) ? v : log1pf(expf(v));
}

// async global->LDS, 16 bytes per lane; LDS dest = wave-uniform base + lane*16
__device__ __forceinline__ void gl2lds16(const unsigned short* g, unsigned short* l) {
    __builtin_amdgcn_global_load_lds(
        (__attribute__((address_space(1))) void*)(void*)g,
        (__attribute__((address_space(3))) void*)(void*)l, 16, 0, 0);
}

// ---------------------------------------------------------------------------
// Merged prepass (unchanged from R8)
// ---------------------------------------------------------------------------
__global__ __launch_bounds__(256) void prepass(
        const float* __restrict__ x, unsigned short* __restrict__ xb,
        const float* __restrict__ W_in, unsigned short* __restrict__ Wt_in,
        const float* __restrict__ W_dt, unsigned short* __restrict__ Wt_cat,
        const float* __restrict__ W_out, unsigned short* __restrict__ Wt_out,
        const float* __restrict__ Wx) {
    __shared__ float tile[32][33];
    const int blk = blockIdx.x;
    const int tid = threadIdx.x;

    if (blk < 2048) {                       // region 0: cvt x
        const size_t i = ((size_t)blk * 256 + tid) * 8;
        const float4 v0 = *(const float4*)(x + i);
        const float4 v1 = *(const float4*)(x + i + 4);
        bf16x8 o;
        o[0] = (short)f2bf(v0.x); o[1] = (short)f2bf(v0.y);
        o[2] = (short)f2bf(v0.z); o[3] = (short)f2bf(v0.w);
        o[4] = (short)f2bf(v1.x); o[5] = (short)f2bf(v1.y);
        o[6] = (short)f2bf(v1.z); o[7] = (short)f2bf(v1.w);
        *(bf16x8*)(xb + i) = o;
        return;
    }
    if (blk < 2048 + 2048 + 1024 + 1024) {  // regions 1-3: transpose
        const float* W; unsigned short* Wt; int N, b;
        if (blk < 4096)      { W = W_in;  Wt = Wt_in;  N = 2048; b = blk - 2048; }
        else if (blk < 5120) { W = W_dt;  Wt = Wt_cat; N = 1024; b = blk - 4096; }
        else                 { W = W_out; Wt = Wt_out; N = 1024; b = blk - 5120; }
        const int nx = N / 32;
        const int n0 = (b % nx) * 32, k0 = (b / nx) * 32;
        const int tx = tid & 31, ty = tid >> 5;
#pragma unroll
        for (int r = 0; r < 4; ++r)
            tile[ty + r * 8][tx] = W[(size_t)(k0 + ty + r * 8) * N + n0 + tx];
        __syncthreads();
#pragma unroll
        for (int r = 0; r < 4; ++r)
            Wt[(size_t)(n0 + ty + r * 8) * 1024 + k0 + tx] = f2bf(tile[tx][ty + r * 8]);
        return;
    }
    {                                        // region 4: wx_stage
        const int idx = (blk - 6144) * 256 + tid;
        const int k = idx & 1023;
        const int n = idx >> 10;
        unsigned short v = 0;
        if (n < 32) v = f2bf(Wx[(size_t)k * 32 + n]);
        Wt_cat[(size_t)(1024 + n) * 1024 + k] = v;
    }
}

// ---------------------------------------------------------------------------
// MFMA GEMM (R8 structure — the measured HIP plateau): 64(M) x 128(N) tile,
// BK=64, 4 waves, double-buffered global_load_lds, one __syncthreads/K-step.
// NEW (R12): 1D grid, m-fast decomposition (mt = bid & 63, nt = bid >> 6).
// Since 64 % 8 == 0, A-tile mt always lands on XCD mt%8 -> the 8.4 MB A
// operand partitions cleanly across per-XCD L2s (1.05 MB each); only the
// small B operand is refetched per XCD. Expect FETCH 42 -> ~28 MB.
// EPI: 0 fp32 store, 2 bf16 store, 3 fused dt/BC.
// ---------------------------------------------------------------------------
template <int EPI>
__global__ __launch_bounds__(256) void gemm64(
        const unsigned short* __restrict__ A, const unsigned short* __restrict__ Bt,
        void* __restrict__ Cout, int N, int K,
        const float* __restrict__ bias, const float* __restrict__ alog,
        float* __restrict__ bc) {
    __shared__ unsigned short As[2][2 * 2048];   // [buf][ks*2048 + row*32 + k]  8 KB/buf
    __shared__ unsigned short Bs[2][2 * 4096];   // [buf][ks*4096 + row*32 + k] 16 KB/buf

    const int tid  = threadIdx.x;
    const int wave = tid >> 6, lane = tid & 63;
    const int q = lane >> 4, mr = lane & 15;
    // m-fast 1D decomposition for XCD-locality of the A operand
    const int bid = blockIdx.x;
    const int m0 = (bid & 63) * 64, n0 = (bid >> 6) * 128;

    f32x4 acc[4][2];
#pragma unroll
    for (int mi = 0; mi < 4; ++mi)
#pragma unroll
        for (int ni = 0; ni < 2; ++ni) acc[mi][ni] = {0.f, 0.f, 0.f, 0.f};

    const int kb = (tid & 3) * 8;
    const int rA = tid >> 2;
    const unsigned short* AgL = A + (size_t)(m0 + rA) * K + kb;
    const unsigned short* AgH = AgL + 32;
    const unsigned short* Bg0L = Bt + (size_t)(n0 + rA) * K + kb;
    const unsigned short* Bg0H = Bg0L + 32;
    const unsigned short* Bg1L = Bt + (size_t)(n0 + 64 + rA) * K + kb;
    const unsigned short* Bg1H = Bg1L + 32;
    const int sT = tid * 8;

    const int NK = K >> 6;   // K / 64
    // prologue: stage k-step 0 into buffer 0
    gl2lds16(AgL, As[0] + sT);
    gl2lds16(AgH, As[0] + 2048 + sT);
    gl2lds16(Bg0L, Bs[0] + sT);
    gl2lds16(Bg1L, Bs[0] + 2048 + sT);
    gl2lds16(Bg0H, Bs[0] + 4096 + sT);
    gl2lds16(Bg1H, Bs[0] + 6144 + sT);

    for (int i = 0; i < NK; ++i) {
        __syncthreads();   // vmcnt drain publishes buf[cur]
        const int cur = i & 1, nxt = cur ^ 1;
        if (i + 1 < NK) {
            const int ko = (i + 1) * 64;
            gl2lds16(AgL + ko, As[nxt] + sT);
            gl2lds16(AgH + ko, As[nxt] + 2048 + sT);
            gl2lds16(Bg0L + ko, Bs[nxt] + sT);
            gl2lds16(Bg1L + ko, Bs[nxt] + 2048 + sT);
            gl2lds16(Bg0H + ko, Bs[nxt] + 4096 + sT);
            gl2lds16(Bg1H + ko, Bs[nxt] + 6144 + sT);
        }
#pragma unroll
        for (int ks = 0; ks < 2; ++ks) {
            bf16x8 af[4], bfr[2];
#pragma unroll
            for (int mi = 0; mi < 4; ++mi)
                af[mi] = *(const bf16x8*)(As[cur] + ks * 2048 + (mi * 16 + mr) * 32 + q * 8);
#pragma unroll
            for (int ni = 0; ni < 2; ++ni)
                bfr[ni] = *(const bf16x8*)(Bs[cur] + ks * 4096 +
                                           (wave * 32 + ni * 16 + mr) * 32 + q * 8);
#pragma unroll
            for (int mi = 0; mi < 4; ++mi)
#pragma unroll
                for (int ni = 0; ni < 2; ++ni)
                    acc[mi][ni] = __builtin_amdgcn_mfma_f32_16x16x32_bf16(
                        af[mi], bfr[ni], acc[mi][ni], 0, 0, 0);
        }
    }

    // epilogue: C/D layout col = lane&15, row = q*4 + r
#pragma unroll
    for (int ni = 0; ni < 2; ++ni) {
        const int col = n0 + wave * 32 + ni * 16 + mr;
        float be = 0.f, al = 0.f;
        if (EPI == 3 && col < 1024) { be = bias[col]; al = alog[col]; }
#pragma unroll
        for (int mi = 0; mi < 4; ++mi) {
            const int row0 = m0 + mi * 16 + q * 4;
#pragma unroll
            for (int r = 0; r < 4; ++r) {
                float v = acc[mi][ni][r];
                const int row = row0 + r;
                if (EPI == 0) {
                    ((float*)Cout)[(size_t)row * N + col] = v;
                } else if (EPI == 2) {
                    ((unsigned short*)Cout)[(size_t)row * N + col] = f2bf(v);
                } else {  // EPI == 3
                    if (col < 1024) {
                        float dt = softplus_f(v + be);
                        ((unsigned short*)Cout)[(size_t)row * 1024 + col] =
                            f2bf(expf(dt * (-expf(al))));
                    } else if (col < 1056) {
                        bc[(size_t)row * 32 + (col - 1024)] = v;
                    }
                }
            }
        }
    }
}

// ---------------------------------------------------------------------------
// Depthwise causal conv (4 taps) + bias + SiLU, bf16 in/out. 8 channels/thread.
// ---------------------------------------------------------------------------
__global__ __launch_bounds__(256) void conv_silu_kernel(
        const unsigned short* __restrict__ xz, const float* __restrict__ conv_w,
        const float* __restrict__ conv_b, unsigned short* __restrict__ xssm) {
    const int idx = blockIdx.x * 256 + threadIdx.x;
    const int d8 = idx & 127;
    const int bt = idx >> 7;
    const int t  = bt & (SEQ - 1);
    const int d  = d8 * 8;

    float4 w[8];
#pragma unroll
    for (int i = 0; i < 8; ++i) w[i] = *(const float4*)&conv_w[(d + i) * 4];

    float acc[8];
    {
        const float4 b0 = *(const float4*)&conv_b[d];
        const float4 b1 = *(const float4*)&conv_b[d + 4];
        acc[0] = b0.x; acc[1] = b0.y; acc[2] = b0.z; acc[3] = b0.w;
        acc[4] = b1.x; acc[5] = b1.y; acc[6] = b1.z; acc[7] = b1.w;
    }

#pragma unroll
    for (int j = 0; j < D_CONV; ++j) {
        const int tt = t - (D_CONV - 1) + j;
        if (tt < 0) continue;
        const bf16x8 xv = *(const bf16x8*)(&xz[((size_t)(bt - t + tt)) * 2048 + d]);
        const float wj[8] = {j == 0 ? w[0].x : j == 1 ? w[0].y : j == 2 ? w[0].z : w[0].w,
                             j == 0 ? w[1].x : j == 1 ? w[1].y : j == 2 ? w[1].z : w[1].w,
                             j == 0 ? w[2].x : j == 1 ? w[2].y : j == 2 ? w[2].z : w[2].w,
                             j == 0 ? w[3].x : j == 1 ? w[3].y : j == 2 ? w[3].z : w[3].w,
                             j == 0 ? w[4].x : j == 1 ? w[4].y : j == 2 ? w[4].z : w[4].w,
                             j == 0 ? w[5].x : j == 1 ? w[5].y : j == 2 ? w[5].z : w[5].w,
                             j == 0 ? w[6].x : j == 1 ? w[6].y : j == 2 ? w[6].z : w[6].w,
                             j == 0 ? w[7].x : j == 1 ? w[7].y : j == 2 ? w[7].z : w[7].w};
#pragma unroll
        for (int i = 0; i < 8; ++i)
            acc[i] += bf2f((unsigned short)xv[i]) * wj[i];
    }
    bf16x8 o;
#pragma unroll
    for (int i = 0; i < 8; ++i) {
        const float s = acc[i] / (1.f + expf(-acc[i]));
        o[i] = (short)f2bf(s);
    }
    *(bf16x8*)(&xssm[(size_t)bt * D_MODEL + d]) = o;
}

// ---------------------------------------------------------------------------
// Chunked selective scan (unchanged)
// ---------------------------------------------------------------------------
__global__ __launch_bounds__(256) void scan_pass1(
        const unsigned short* __restrict__ xssm, const unsigned short* __restrict__ dA16,
        const float* __restrict__ BCb,
        float* __restrict__ Sbuf, float* __restrict__ Pbuf) {
    const int ch = blockIdx.x, dg = blockIdx.y, b = blockIdx.z;
    const int tid = threadIdx.x;
    const int dd  = dg * 256 + tid;
    const int t0  = ch * CHUNK;

    __shared__ float Bs[CHUNK][16];
    if (tid < CHUNK * 4) {
        const int t = tid >> 2, j = (tid & 3) * 4;
        *(float4*)&Bs[t][j] = *(const float4*)&BCb[((size_t)b * SEQ + t0 + t) * 32 + j];
    }
    __syncthreads();

    const size_t base = ((size_t)b * SEQ + t0) * D_MODEL + dd;
    float h[16];
#pragma unroll
    for (int n = 0; n < 16; ++n) h[n] = 0.f;
    float P = 1.f;

    for (int g = 0; g < CHUNK; g += 8) {
        float dAr[8], xr[8];
#pragma unroll
        for (int p = 0; p < 8; ++p) {
            const size_t o = base + (size_t)(g + p) * D_MODEL;
            dAr[p] = bf2f(dA16[o]);
            xr[p]  = bf2f(xssm[o]);
        }
#pragma unroll
        for (int p = 0; p < 8; ++p) {
            const int t = g + p;
            const float dA = dAr[p], x = xr[p];
            P *= dA;
            const float4 B0 = *(const float4*)&Bs[t][0];
            const float4 B1 = *(const float4*)&Bs[t][4];
            const float4 B2 = *(const float4*)&Bs[t][8];
            const float4 B3 = *(const float4*)&Bs[t][12];
            h[0]  = h[0]  * dA + x * B0.x;  h[1]  = h[1]  * dA + x * B0.y;
            h[2]  = h[2]  * dA + x * B0.z;  h[3]  = h[3]  * dA + x * B0.w;
            h[4]  = h[4]  * dA + x * B1.x;  h[5]  = h[5]  * dA + x * B1.y;
            h[6]  = h[6]  * dA + x * B1.z;  h[7]  = h[7]  * dA + x * B1.w;
            h[8]  = h[8]  * dA + x * B2.x;  h[9]  = h[9]  * dA + x * B2.y;
            h[10] = h[10] * dA + x * B2.z;  h[11] = h[11] * dA + x * B2.w;
            h[12] = h[12] * dA + x * B3.x;  h[13] = h[13] * dA + x * B3.y;
            h[14] = h[14] * dA + x * B3.z;  h[15] = h[15] * dA + x * B3.w;
        }
    }

    const int dn = b * D_MODEL + dd;
    const size_t so = ((size_t)ch * BD + dn) * 16;
#pragma unroll
    for (int n = 0; n < 16; n += 4)
        *(float4*)&Sbuf[so + n] = make_float4(h[n], h[n + 1], h[n + 2], h[n + 3]);
    Pbuf[(size_t)ch * BD + dn] = P;
}

// Sequential combine over chunks. Thread per (b,d,n) = 32768 threads.
__global__ __launch_bounds__(128) void scan_mid(
        const float* __restrict__ Sbuf, const float* __restrict__ Pbuf,
        float* __restrict__ Hin) {
    const int idx = blockIdx.x * 128 + threadIdx.x;
    const int n   = idx & 15;
    const int dn  = idx >> 4;

    float h = 0.f;
    for (int ch = 0; ch < NCHUNK; ++ch) {
        const size_t s = ((size_t)ch * BD + dn) * 16 + n;
        Hin[s] = h;
        h = Pbuf[(size_t)ch * BD + dn] * h + Sbuf[s];
    }
}

__global__ __launch_bounds__(256) void scan_pass2(
        const unsigned short* __restrict__ xssm, const unsigned short* __restrict__ dA16,
        const float* __restrict__ BCb, const unsigned short* __restrict__ xz,
        const float* __restrict__ Dp, const float* __restrict__ Hin,
        unsigned short* __restrict__ ybuf) {
    const int ch = blockIdx.x, dg = blockIdx.y, b = blockIdx.z;
    const int tid = threadIdx.x;
    const int dd  = dg * 256 + tid;
    const int t0  = ch * CHUNK;

    __shared__ float BCs[CHUNK][32];
    {
        const int t = tid >> 3, j = (tid & 7) * 4;
        *(float4*)&BCs[t][j] = *(const float4*)&BCb[((size_t)b * SEQ + t0 + t) * 32 + j];
    }
    __syncthreads();

    const float Dpv = Dp[dd];
    const size_t base  = ((size_t)b * SEQ + t0) * D_MODEL + dd;
    const size_t baseZ = ((size_t)b * SEQ + t0) * 2048 + D_MODEL + dd;

    float h[16];
    const int dn = b * D_MODEL + dd;
    const size_t ho = ((size_t)ch * BD + dn) * 16;
#pragma unroll
    for (int n = 0; n < 16; n += 4) {
        const float4 hv = *(const float4*)&Hin[ho + n];
        h[n] = hv.x; h[n + 1] = hv.y; h[n + 2] = hv.z; h[n + 3] = hv.w;
    }

    for (int g = 0; g < CHUNK; g += 8) {
        float dAr[8], xr[8], zr[8];
#pragma unroll
        for (int p = 0; p < 8; ++p) {
            const size_t o = base + (size_t)(g + p) * D_MODEL;
            dAr[p] = bf2f(dA16[o]);
            xr[p]  = bf2f(xssm[o]);
            zr[p]  = bf2f(xz[baseZ + (size_t)(g + p) * 2048]);
        }
#pragma unroll
        for (int p = 0; p < 8; ++p) {
            const int t = g + p;
            const float dA = dAr[p], x = xr[p];
            const float4 B0 = *(const float4*)&BCs[t][0];
            const float4 B1 = *(const float4*)&BCs[t][4];
            const float4 B2 = *(const float4*)&BCs[t][8];
            const float4 B3 = *(const float4*)&BCs[t][12];
            const float4 C0 = *(const float4*)&BCs[t][16];
            const float4 C1 = *(const float4*)&BCs[t][20];
            const float4 C2 = *(const float4*)&BCs[t][24];
            const float4 C3 = *(const float4*)&BCs[t][28];
            float y = 0.f;
            h[0]  = h[0]  * dA + x * B0.x;  y += h[0]  * C0.x;
            h[1]  = h[1]  * dA + x * B0.y;  y += h[1]  * C0.y;
            h[2]  = h[2]  * dA + x * B0.z;  y += h[2]  * C0.z;
            h[3]  = h[3]  * dA + x * B0.w;  y += h[3]  * C0.w;
            h[4]  = h[4]  * dA + x * B1.x;  y += h[4]  * C1.x;
            h[5]  = h[5]  * dA + x * B1.y;  y += h[5]  * C1.y;
            h[6]  = h[6]  * dA + x * B1.z;  y += h[6]  * C1.z;
            h[7]  = h[7]  * dA + x * B1.w;  y += h[7]  * C1.w;
            h[8]  = h[8]  * dA + x * B2.x;  y += h[8]  * C2.x;
            h[9]  = h[9]  * dA + x * B2.y;  y += h[9]  * C2.y;
            h[10] = h[10] * dA + x * B2.z;  y += h[10] * C2.z;
            h[11] = h[11] * dA + x * B2.w;  y += h[11] * C2.w;
            h[12] = h[12] * dA + x * B3.x;  y += h[12] * C3.x;
            h[13] = h[13] * dA + x * B3.y;  y += h[13] * C3.y;
            h[14] = h[14] * dA + x * B3.z;  y += h[14] * C3.z;
            h[15] = h[15] * dA + x * B3.w;  y += h[15] * C3.w;

            const float zv = zr[p];
            const float sz = zv / (1.f + expf(-zv));
            ybuf[base + (size_t)t * D_MODEL] = f2bf((y + x * Dpv) * sz);
        }
    }
}

// ---------------------------------------------------------------------------
extern "C" void kernel_launch(void* const* d_in, const int* in_sizes, int n_in,
                              void* d_out, int out_size, void* d_ws, size_t ws_size,
                              hipStream_t stream) {
    const float* x       = (const float*)d_in[0];
    const float* W_in    = (const float*)d_in[1];
    const float* conv_w  = (const float*)d_in[2];
    const float* conv_b  = (const float*)d_in[3];
    const float* W_x     = (const float*)d_in[4];
    const float* W_dt    = (const float*)d_in[5];
    const float* b_dt    = (const float*)d_in[6];
    const float* A_log   = (const float*)d_in[7];
    const float* D_param = (const float*)d_in[8];
    const float* W_out   = (const float*)d_in[9];
    float* out = (float*)d_out;
    char* ws   = (char*)d_ws;

    unsigned short* xz_bf   = (unsigned short*)(ws + 0);
    unsigned short* xssm_bf = (unsigned short*)(ws + 16777216);
    unsigned short* dAb16   = (unsigned short*)(ws + 25165824);
    float*          BCb     = (float*)(ws + 41943040);
    unsigned short* ybuf_bf = (unsigned short*)(ws + 42467328);
    unsigned short* xb      = (unsigned short*)(ws + 50855936);
    unsigned short* Wt_in   = (unsigned short*)(ws + 59244544);
    unsigned short* Wt_cat  = (unsigned short*)(ws + 63438848);
    unsigned short* Wt_out  = (unsigned short*)(ws + 65798144);
    float*          Sbuf    = (float*)(ws + 67895296);
    float*          Pbuf    = (float*)(ws + 76283904);
    float*          Hin     = (float*)(ws + 76808192);

    // 0. merged prepass
    prepass<<<2048 + 2048 + 1024 + 1024 + 512, 256, 0, stream>>>(
        x, xb, W_in, Wt_in, W_dt, Wt_cat, W_out, Wt_out, W_x);

    // 1. xz = x @ W_in  (bf16 out) — 1D grid, m-fast (16 n-tiles x 64 m-tiles)
    gemm64<2><<<16 * 64, 256, 0, stream>>>(
        xb, Wt_in, xz_bf, 2048, D_MODEL, nullptr, nullptr, nullptr);
    // 2. depthwise conv + silu
    conv_silu_kernel<<<(MROWS * 128) / 256, 256, 0, stream>>>(xz_bf, conv_w, conv_b, xssm_bf);
    // 3. fused dt/BC GEMM — 9 n-tiles x 64 m-tiles
    gemm64<3><<<9 * 64, 256, 0, stream>>>(
        xssm_bf, Wt_cat, dAb16, 1152, D_MODEL, b_dt, A_log, BCb);
    // 4. chunked selective scan
    scan_pass1<<<dim3(NCHUNK, D_MODEL / 256, BATCH), 256, 0, stream>>>(
        xssm_bf, dAb16, BCb, Sbuf, Pbuf);
    scan_mid<<<(BD * 16) / 128, 128, 0, stream>>>(Sbuf, Pbuf, Hin);
    scan_pass2<<<dim3(NCHUNK, D_MODEL / 256, BATCH), 256, 0, stream>>>(
        xssm_bf, dAb16, BCb, xz_bf, D_param, Hin, ybuf_bf);
    // 5. out = y @ W_out — 8 n-tiles x 64 m-tiles
    gemm64<0><<<8 * 64, 256, 0, stream>>>(
        ybuf_bf, Wt_out, out, D_MODEL, D_MODEL, nullptr, nullptr, nullptr);
}